// Round 3
// baseline (333.839 us; speedup 1.0000x reference)
//
#include <hip/hip_runtime.h>
#include <math.h>

#define NB 8192      // batch rows
#define NC 1000      // classes
#define NF4 250      // NC / 4 float4s per row

// ws layout (floats, stride NB):
//  [0..4]   margin per branch
//  [5..9]   gathered (raw) per branch
//  [10..14] KD per branch
//  [15]     CE
//  at float offset 16*NB: two uints {minkey, maxkey} (order-preserving float keys)

#define LOG2E 1.4426950408889634f
#define LN2   0.6931471805599453f

__device__ __forceinline__ float fexp2(float x) { return __builtin_amdgcn_exp2f(x); }
__device__ __forceinline__ float flog2(float x) { return __builtin_amdgcn_logf(x); }

// order-preserving float<->uint key (for atomicMin/Max on floats incl. negatives)
__device__ __forceinline__ unsigned fkey(float f) {
  unsigned u = __float_as_uint(f);
  return (u & 0x80000000u) ? ~u : (u | 0x80000000u);
}
__device__ __forceinline__ float funkey(unsigned k) {
  return __uint_as_float((k & 0x80000000u) ? (k ^ 0x80000000u) : ~k);
}

__device__ __forceinline__ float wredsum(float v) {
#pragma unroll
  for (int m = 32; m >= 1; m >>= 1) v += __shfl_xor(v, m, 64);
  return v;
}
__device__ __forceinline__ void wredtop2(float& t1, float& t2) {
#pragma unroll
  for (int m = 32; m >= 1; m >>= 1) {
    float o1 = __shfl_xor(t1, m, 64);
    float o2 = __shfl_xor(t2, m, 64);
    float lo = fminf(t1, o1);
    t1 = fmaxf(t1, o1);
    t2 = fmaxf(fmaxf(t2, o2), lo);
  }
}
__device__ __forceinline__ float f4get(const float4& v, int e) {
  return e == 0 ? v.x : e == 1 ? v.y : e == 2 ? v.z : v.w;
}
__device__ __forceinline__ float uload(const float* p) {  // wave-uniform load -> SGPR
  return __uint_as_float(__builtin_amdgcn_readfirstlane(__float_as_uint(*p)));
}

// tiny init: seed the atomic min/max cells and zero the output scalar
__global__ void k_init(float* __restrict__ ws, float* __restrict__ out) {
  if (threadIdx.x == 0) {
    unsigned* scal = (unsigned*)(ws + (size_t)16 * NB);
    scal[0] = 0xFFFFFFFFu;  // minkey
    scal[1] = 0u;           // maxkey
    out[0] = 0.0f;
  }
}

// One wave per row; single fused streaming pass (no max-shift needed:
// inputs are ~N(0,1), T=20 / T=1 exponents can't overflow f32).
__global__ __launch_bounds__(256) void k_rowstats(
    const float* __restrict__ o1, const float* __restrict__ o2,
    const float* __restrict__ o3, const float* __restrict__ o4,
    const float* __restrict__ os, const int* __restrict__ tg,
    float* __restrict__ ws) {
  const int lane = threadIdx.x & 63;
  const int row = blockIdx.x * 4 + (threadIdx.x >> 6);
  const size_t base = (size_t)row * NC;

  // wave-uniform target gathers -> SGPRs (issued first, overlap everything)
  const int target = tg[row];
  const float g1 = uload(o1 + base + target);
  const float g2 = uload(o2 + base + target);
  const float g3 = uload(o3 + base + target);
  const float g4 = uload(o4 + base + target);
  const float gs = uload(os + base + target);

  const float4* p1 = (const float4*)(o1 + base);
  const float4* p2 = (const float4*)(o2 + base);
  const float4* p3 = (const float4*)(o3 + base);
  const float4* p4 = (const float4*)(o4 + base);
  const float4* ps = (const float4*)(os + base);

  // online state
  float t1[5], t2[5], Z[5], S1[5];
#pragma unroll
  for (int t = 0; t < 5; ++t) {
    t1[t] = -INFINITY; t2[t] = -INFINITY; Z[t] = 0.f; S1[t] = 0.f;
  }
  float Z1 = 0.f, Z20 = 0.f;
  const float K20 = LOG2E / 20.0f;

  // 1-deep software pipeline over 4 chunks of 64 float4s
  float4 c1 = p1[lane], c2 = p2[lane], c3 = p3[lane], c4 = p4[lane], cs = ps[lane];
#pragma unroll 1
  for (int j = 0; j < 4; ++j) {
    float4 n1 = c1, n2 = c2, n3 = c3, n4 = c4, ns = cs;
    if (j < 3) {
      int fn = (j + 1) * 64 + lane;
      int fc = fn < NF4 ? fn : 0;
      n1 = p1[fc]; n2 = p2[fc]; n3 = p3[fc]; n4 = p4[fc]; ns = ps[fc];
    }
    if (j * 64 + lane < NF4) {
#pragma unroll
      for (int e = 0; e < 4; ++e) {
        float w0 = f4get(c1, e);
        float w1 = f4get(c2, e);
        float w2 = f4get(c3, e);
        float w3 = f4get(c4, e);
        float wsv = f4get(cs, e);
        float wm = ((w0 + w1) + w2 + w3) * 0.25f;  // mimic — keep this op order
        float w[5] = {w0, w1, w2, w3, wm};
#pragma unroll
        for (int t = 0; t < 5; ++t) {
          t2[t] = fmaxf(t2[t], fminf(t1[t], w[t]));
          t1[t] = fmaxf(t1[t], w[t]);
          float et = fexp2(w[t] * K20);
          Z[t] += et;
          S1[t] = fmaf(et, w[t] - wsv, S1[t]);
        }
        Z1 += fexp2(wsv * LOG2E);
        Z20 += fexp2(wsv * K20);
      }
    }
    c1 = n1; c2 = n2; c3 = n3; c4 = n4; cs = ns;
  }

#pragma unroll
  for (int t = 0; t < 5; ++t) wredtop2(t1[t], t2[t]);
#pragma unroll
  for (int t = 0; t < 5; ++t) { Z[t] = wredsum(Z[t]); S1[t] = wredsum(S1[t]); }
  Z1 = wredsum(Z1);
  Z20 = wredsum(Z20);

  if (lane == 0) {
    const float gm = ((g1 + g2) + g3 + g4) * 0.25f;
    float gg[5] = {g1, g2, g3, g4, gm};

    const float lse_s = flog2(Z20) * LN2;       // logsumexp(out_s/20), unshifted
    const float CE = flog2(Z1) * LN2 - gs;      // -log_softmax(out_s)[target]

#pragma unroll
    for (int t = 0; t < 5; ++t) {
      float lse_t = flog2(Z[t]) * LN2;
      float KD = 400.0f * (S1[t] / (20.0f * Z[t]) - lse_t + lse_s);
      float margin = (t1[t] == gg[t]) ? (t1[t] - t2[t]) : 0.0f;
      ws[(size_t)t * NB + row] = margin;
      ws[(size_t)(5 + t) * NB + row] = gg[t];
      ws[(size_t)(10 + t) * NB + row] = KD;
    }
    ws[(size_t)15 * NB + row] = CE;

    unsigned* scal = (unsigned*)(ws + (size_t)16 * NB);
    atomicMin(&scal[0], fkey(fminf(fminf(g1, g2), fminf(g3, g4))));
    atomicMax(&scal[1], fkey(fmaxf(fmaxf(t1[0], t1[1]), fmaxf(t1[2], t1[3]))));
  }
}

// Multi-block weighted-loss reduction; one atomicAdd per block.
__global__ __launch_bounds__(256) void k_loss(const float* __restrict__ ws,
                                              float* __restrict__ out) {
  const int tid = threadIdx.x;
  const int lane = tid & 63, wv = tid >> 6;
  const int r = blockIdx.x * 256 + tid;   // 32 blocks x 256 = 8192 rows
  __shared__ float sA[4];

  const unsigned* scal = (const unsigned*)(ws + (size_t)16 * NB);
  const float mn = funkey(scal[0]);
  const float mx = funkey(scal[1]);
  const float shift = (mn < 0.0f) ? (-mn + 1e-5f) : 0.0f;
  const float maxp = mx + shift;
  const float K6 = LOG2E / 6.0f;

  float m[5], e[5];
#pragma unroll
  for (int t = 0; t < 5; ++t) m[t] = ws[(size_t)t * NB + r];
  float pm = fmaxf(fmaxf(fmaxf(m[0], m[1]), fmaxf(m[2], m[3])), m[4]);
  float Zl = 0.0f;
#pragma unroll
  for (int t = 0; t < 5; ++t) { e[t] = fexp2((m[t] - pm) * K6); Zl += e[t]; }
  float ce = ws[(size_t)15 * NB + r];
  float rl = 0.0f;
#pragma unroll
  for (int t = 0; t < 5; ++t) {
    float g = ws[(size_t)(5 + t) * NB + r];
    float kd = ws[(size_t)(10 + t) * NB + r];
    float w2 = (g + shift) / maxp;
    float loss = (1.0f - w2) * ce + w2 * kd;
    rl += e[t] * loss;
  }
  float acc = rl / Zl;

  acc = wredsum(acc);
  if (lane == 0) sA[wv] = acc;
  __syncthreads();
  if (tid == 0) {
    float tot = (sA[0] + sA[1]) + (sA[2] + sA[3]);
    atomicAdd(out, tot * (1.0f / 8192.0f));
  }
}

extern "C" void kernel_launch(void* const* d_in, const int* in_sizes, int n_in,
                              void* d_out, int out_size, void* d_ws, size_t ws_size,
                              hipStream_t stream) {
  const float* o1 = (const float*)d_in[0];
  const float* o2 = (const float*)d_in[1];
  const float* o3 = (const float*)d_in[2];
  const float* o4 = (const float*)d_in[3];
  const float* os = (const float*)d_in[4];
  const int* tg = (const int*)d_in[5];
  float* ws = (float*)d_ws;
  float* out = (float*)d_out;

  k_init<<<1, 64, 0, stream>>>(ws, out);
  k_rowstats<<<NB / 4, 256, 0, stream>>>(o1, o2, o3, o4, os, tg, ws);
  k_loss<<<NB / 256, 256, 0, stream>>>(ws, out);
}

// Round 4
// 325.359 us; speedup vs baseline: 1.0261x; 1.0261x over previous
//
#include <hip/hip_runtime.h>
#include <math.h>

#define NB 8192      // batch rows
#define NC 1000      // classes
#define NF4 250      // NC / 4 float4s per row

// ws layout (floats, stride NB):
//  [0..4]   margin per branch
//  [5..9]   gathered (raw) per branch
//  [10..14] KD per branch
//  [15]     CE
//  at float offset 16*NB: two uints {minkey, maxkey} (order-preserving float keys)

#define LOG2E 1.4426950408889634f
#define LN2   0.6931471805599453f

__device__ __forceinline__ float fexp2(float x) { return __builtin_amdgcn_exp2f(x); }
__device__ __forceinline__ float flog2(float x) { return __builtin_amdgcn_logf(x); }

// order-preserving float<->uint key (for atomicMin/Max on floats incl. negatives)
__device__ __forceinline__ unsigned fkey(float f) {
  unsigned u = __float_as_uint(f);
  return (u & 0x80000000u) ? ~u : (u | 0x80000000u);
}
__device__ __forceinline__ float funkey(unsigned k) {
  return __uint_as_float((k & 0x80000000u) ? (k ^ 0x80000000u) : ~k);
}

__device__ __forceinline__ float wredsum(float v) {
#pragma unroll
  for (int m = 32; m >= 1; m >>= 1) v += __shfl_xor(v, m, 64);
  return v;
}
__device__ __forceinline__ void wredtop2(float& t1, float& t2) {
#pragma unroll
  for (int m = 32; m >= 1; m >>= 1) {
    float o1 = __shfl_xor(t1, m, 64);
    float o2 = __shfl_xor(t2, m, 64);
    float lo = fminf(t1, o1);
    t1 = fmaxf(t1, o1);
    t2 = fmaxf(fmaxf(t2, o2), lo);
  }
}
__device__ __forceinline__ float f4get(const float4& v, int e) {
  return e == 0 ? v.x : e == 1 ? v.y : e == 2 ? v.z : v.w;
}

// tiny init: seed the atomic min/max cells and zero the output scalar
__global__ void k_init(float* __restrict__ ws, float* __restrict__ out) {
  if (threadIdx.x == 0) {
    unsigned* scal = (unsigned*)(ws + (size_t)16 * NB);
    scal[0] = 0xFFFFFFFFu;  // minkey
    scal[1] = 0u;           // maxkey
    out[0] = 0.0f;
  }
}

// One BLOCK (4 waves) per row: each lane holds exactly one float4 per tensor
// (5 float4s = 20 data VGPRs). Unshifted exp sums (inputs ~N(0,1): safe,
// absmax=0 verified in R3). Cross-wave combine via LDS.
__global__ __launch_bounds__(256) void k_rowstats(
    const float* __restrict__ o1, const float* __restrict__ o2,
    const float* __restrict__ o3, const float* __restrict__ o4,
    const float* __restrict__ os, const int* __restrict__ tg,
    float* __restrict__ ws) {
  const int lane = threadIdx.x & 63;
  const int wv = threadIdx.x >> 6;         // 0..3
  const int row = blockIdx.x;
  const size_t base = (size_t)row * NC;
  const int f = (threadIdx.x < NF4) ? (int)threadIdx.x : 0;  // float4 idx
  const bool act = threadIdx.x < NF4;

  // target gathers: only wave 0 needs them (for the final combine) — issue first
  float g1 = 0.f, g2 = 0.f, g3 = 0.f, g4 = 0.f, gs = 0.f;
  if (wv == 0) {
    const int target = tg[row];
    g1 = o1[base + target];
    g2 = o2[base + target];
    g3 = o3[base + target];
    g4 = o4[base + target];
    gs = os[base + target];
  }

  // bulk loads: 5 float4s per lane, all in flight at once
  const float4 c1 = ((const float4*)(o1 + base))[f];
  const float4 c2 = ((const float4*)(o2 + base))[f];
  const float4 c3 = ((const float4*)(o3 + base))[f];
  const float4 c4 = ((const float4*)(o4 + base))[f];
  const float4 cs = ((const float4*)(os + base))[f];

  float t1[5], t2[5], Z[5], S1[5];
#pragma unroll
  for (int t = 0; t < 5; ++t) {
    t1[t] = -INFINITY; t2[t] = -INFINITY; Z[t] = 0.f; S1[t] = 0.f;
  }
  float Z1 = 0.f, Z20 = 0.f;
  const float K20 = LOG2E / 20.0f;

  if (act) {
#pragma unroll
    for (int e = 0; e < 4; ++e) {
      float w0 = f4get(c1, e);
      float w1 = f4get(c2, e);
      float w2 = f4get(c3, e);
      float w3 = f4get(c4, e);
      float wsv = f4get(cs, e);
      float wm = ((w0 + w1) + w2 + w3) * 0.25f;  // mimic — keep this op order
      float w[5] = {w0, w1, w2, w3, wm};
#pragma unroll
      for (int t = 0; t < 5; ++t) {
        t2[t] = fmaxf(t2[t], fminf(t1[t], w[t]));
        t1[t] = fmaxf(t1[t], w[t]);
        float et = fexp2(w[t] * K20);
        Z[t] += et;
        S1[t] = fmaf(et, w[t] - wsv, S1[t]);
      }
      Z1 += fexp2(wsv * LOG2E);
      Z20 += fexp2(wsv * K20);
    }
  }

  // wave-level reductions
#pragma unroll
  for (int t = 0; t < 5; ++t) wredtop2(t1[t], t2[t]);
#pragma unroll
  for (int t = 0; t < 5; ++t) { Z[t] = wredsum(Z[t]); S1[t] = wredsum(S1[t]); }
  Z1 = wredsum(Z1);
  Z20 = wredsum(Z20);

  // cross-wave combine via LDS: 22 partials per wave
  __shared__ float sred[4][22];
  if (lane == 0) {
#pragma unroll
    for (int t = 0; t < 5; ++t) {
      sred[wv][t] = t1[t];
      sred[wv][5 + t] = t2[t];
      sred[wv][10 + t] = Z[t];
      sred[wv][15 + t] = S1[t];
    }
    sred[wv][20] = Z1;
    sred[wv][21] = Z20;
  }
  __syncthreads();

  if (threadIdx.x == 0) {
    float T1[5], T2[5], ZZ[5], SS[5], z1, z20;
#pragma unroll
    for (int t = 0; t < 5; ++t) {
      T1[t] = sred[0][t]; T2[t] = sred[0][5 + t];
      ZZ[t] = sred[0][10 + t]; SS[t] = sred[0][15 + t];
    }
    z1 = sred[0][20]; z20 = sred[0][21];
#pragma unroll
    for (int w = 1; w < 4; ++w) {
#pragma unroll
      for (int t = 0; t < 5; ++t) {
        float a1 = sred[w][t], a2 = sred[w][5 + t];
        float lo = fminf(T1[t], a1);
        T1[t] = fmaxf(T1[t], a1);
        T2[t] = fmaxf(fmaxf(T2[t], a2), lo);
        ZZ[t] += sred[w][10 + t];
        SS[t] += sred[w][15 + t];
      }
      z1 += sred[w][20];
      z20 += sred[w][21];
    }

    const float gm = ((g1 + g2) + g3 + g4) * 0.25f;  // same op order as wm
    float gg[5] = {g1, g2, g3, g4, gm};

    const float lse_s = flog2(z20) * LN2;      // logsumexp(out_s/20), unshifted
    const float CE = flog2(z1) * LN2 - gs;     // -log_softmax(out_s)[target]

#pragma unroll
    for (int t = 0; t < 5; ++t) {
      float lse_t = flog2(ZZ[t]) * LN2;
      float KD = 400.0f * (SS[t] / (20.0f * ZZ[t]) - lse_t + lse_s);
      float margin = (T1[t] == gg[t]) ? (T1[t] - T2[t]) : 0.0f;
      ws[(size_t)t * NB + row] = margin;
      ws[(size_t)(5 + t) * NB + row] = gg[t];
      ws[(size_t)(10 + t) * NB + row] = KD;
    }
    ws[(size_t)15 * NB + row] = CE;

    unsigned* scal = (unsigned*)(ws + (size_t)16 * NB);
    atomicMin(&scal[0], fkey(fminf(fminf(g1, g2), fminf(g3, g4))));
    atomicMax(&scal[1], fkey(fmaxf(fmaxf(T1[0], T1[1]), fmaxf(T1[2], T1[3]))));
  }
}

// Multi-block weighted-loss reduction; one atomicAdd per block.
__global__ __launch_bounds__(256) void k_loss(const float* __restrict__ ws,
                                              float* __restrict__ out) {
  const int tid = threadIdx.x;
  const int lane = tid & 63, wv = tid >> 6;
  const int r = blockIdx.x * 256 + tid;   // 32 blocks x 256 = 8192 rows
  __shared__ float sA[4];

  const unsigned* scal = (const unsigned*)(ws + (size_t)16 * NB);
  const float mn = funkey(scal[0]);
  const float mx = funkey(scal[1]);
  const float shift = (mn < 0.0f) ? (-mn + 1e-5f) : 0.0f;
  const float maxp = mx + shift;
  const float K6 = LOG2E / 6.0f;

  float m[5], e[5];
#pragma unroll
  for (int t = 0; t < 5; ++t) m[t] = ws[(size_t)t * NB + r];
  float pm = fmaxf(fmaxf(fmaxf(m[0], m[1]), fmaxf(m[2], m[3])), m[4]);
  float Zl = 0.0f;
#pragma unroll
  for (int t = 0; t < 5; ++t) { e[t] = fexp2((m[t] - pm) * K6); Zl += e[t]; }
  float ce = ws[(size_t)15 * NB + r];
  float rl = 0.0f;
#pragma unroll
  for (int t = 0; t < 5; ++t) {
    float g = ws[(size_t)(5 + t) * NB + r];
    float kd = ws[(size_t)(10 + t) * NB + r];
    float w2 = (g + shift) / maxp;
    float loss = (1.0f - w2) * ce + w2 * kd;
    rl += e[t] * loss;
  }
  float acc = rl / Zl;

  acc = wredsum(acc);
  if (lane == 0) sA[wv] = acc;
  __syncthreads();
  if (tid == 0) {
    float tot = (sA[0] + sA[1]) + (sA[2] + sA[3]);
    atomicAdd(out, tot * (1.0f / 8192.0f));
  }
}

extern "C" void kernel_launch(void* const* d_in, const int* in_sizes, int n_in,
                              void* d_out, int out_size, void* d_ws, size_t ws_size,
                              hipStream_t stream) {
  const float* o1 = (const float*)d_in[0];
  const float* o2 = (const float*)d_in[1];
  const float* o3 = (const float*)d_in[2];
  const float* o4 = (const float*)d_in[3];
  const float* os = (const float*)d_in[4];
  const int* tg = (const int*)d_in[5];
  float* ws = (float*)d_ws;
  float* out = (float*)d_out;

  k_init<<<1, 64, 0, stream>>>(ws, out);
  k_rowstats<<<NB, 256, 0, stream>>>(o1, o2, o3, o4, os, tg, ws);
  k_loss<<<NB / 256, 256, 0, stream>>>(ws, out);
}

// Round 5
// 194.194 us; speedup vs baseline: 1.7191x; 1.6754x over previous
//
#include <hip/hip_runtime.h>
#include <math.h>

#define NB 8192      // batch rows
#define NC 1000      // classes
#define NF4 250      // NC / 4 float4s per row

// ws layout (floats, stride NB):
//  [0..4]   margin per branch
//  [5..9]   gathered (raw) per branch
//  [10..14] KD per branch
//  [15]     CE
//  [16]     row min of gathered over 4 real teachers
//  [17]     row max of row-maxes over 4 real teachers
//  [18*NB + 0] shift  (written by k_minmax)
//  [18*NB + 1] maxp   (written by k_minmax)

#define LOG2E 1.4426950408889634f
#define LN2   0.6931471805599453f

__device__ __forceinline__ float fexp2(float x) { return __builtin_amdgcn_exp2f(x); }
__device__ __forceinline__ float flog2(float x) { return __builtin_amdgcn_logf(x); }

__device__ __forceinline__ float wredsum(float v) {
#pragma unroll
  for (int m = 32; m >= 1; m >>= 1) v += __shfl_xor(v, m, 64);
  return v;
}
__device__ __forceinline__ float wredmax(float v) {
#pragma unroll
  for (int m = 32; m >= 1; m >>= 1) v = fmaxf(v, __shfl_xor(v, m, 64));
  return v;
}
__device__ __forceinline__ float wredmin(float v) {
#pragma unroll
  for (int m = 32; m >= 1; m >>= 1) v = fminf(v, __shfl_xor(v, m, 64));
  return v;
}
__device__ __forceinline__ void wredtop2(float& t1, float& t2) {
#pragma unroll
  for (int m = 32; m >= 1; m >>= 1) {
    float o1 = __shfl_xor(t1, m, 64);
    float o2 = __shfl_xor(t2, m, 64);
    float lo = fminf(t1, o1);
    t1 = fmaxf(t1, o1);
    t2 = fmaxf(fmaxf(t2, o2), lo);
  }
}
__device__ __forceinline__ float f4get(const float4& v, int e) {
  return e == 0 ? v.x : e == 1 ? v.y : e == 2 ? v.z : v.w;
}

// One BLOCK (4 waves) per row: each lane holds one float4 per tensor.
// Unshifted exp sums (inputs ~N(0,1): safe; absmax=0 verified R3/R4).
// NO global atomics here — per-row min/max go to ws (R3/R4 regression was
// hot-cell atomicMin/Max contention, ~+140 us).
__global__ __launch_bounds__(256) void k_rowstats(
    const float* __restrict__ o1, const float* __restrict__ o2,
    const float* __restrict__ o3, const float* __restrict__ o4,
    const float* __restrict__ os, const int* __restrict__ tg,
    float* __restrict__ ws) {
  const int lane = threadIdx.x & 63;
  const int wv = threadIdx.x >> 6;         // 0..3
  const int row = blockIdx.x;
  const size_t base = (size_t)row * NC;
  const int f = (threadIdx.x < NF4) ? (int)threadIdx.x : 0;  // float4 idx
  const bool act = threadIdx.x < NF4;

  // target gathers: only wave 0 needs them — issue first, overlap bulk loads
  float g1 = 0.f, g2 = 0.f, g3 = 0.f, g4 = 0.f, gs = 0.f;
  if (wv == 0) {
    const int target = tg[row];
    g1 = o1[base + target];
    g2 = o2[base + target];
    g3 = o3[base + target];
    g4 = o4[base + target];
    gs = os[base + target];
  }

  // bulk loads: 5 float4s per lane, all in flight at once
  const float4 c1 = ((const float4*)(o1 + base))[f];
  const float4 c2 = ((const float4*)(o2 + base))[f];
  const float4 c3 = ((const float4*)(o3 + base))[f];
  const float4 c4 = ((const float4*)(o4 + base))[f];
  const float4 cs = ((const float4*)(os + base))[f];

  float t1[5], t2[5], Z[5], S1[5];
#pragma unroll
  for (int t = 0; t < 5; ++t) {
    t1[t] = -INFINITY; t2[t] = -INFINITY; Z[t] = 0.f; S1[t] = 0.f;
  }
  float Z1 = 0.f, Z20 = 0.f;
  const float K20 = LOG2E / 20.0f;

  if (act) {
#pragma unroll
    for (int e = 0; e < 4; ++e) {
      float w0 = f4get(c1, e);
      float w1 = f4get(c2, e);
      float w2 = f4get(c3, e);
      float w3 = f4get(c4, e);
      float wsv = f4get(cs, e);
      float wm = ((w0 + w1) + w2 + w3) * 0.25f;  // mimic — keep this op order
      float w[5] = {w0, w1, w2, w3, wm};
#pragma unroll
      for (int t = 0; t < 5; ++t) {
        t2[t] = fmaxf(t2[t], fminf(t1[t], w[t]));
        t1[t] = fmaxf(t1[t], w[t]);
        float et = fexp2(w[t] * K20);
        Z[t] += et;
        S1[t] = fmaf(et, w[t] - wsv, S1[t]);
      }
      Z1 += fexp2(wsv * LOG2E);
      Z20 += fexp2(wsv * K20);
    }
  }

  // wave-level reductions
#pragma unroll
  for (int t = 0; t < 5; ++t) wredtop2(t1[t], t2[t]);
#pragma unroll
  for (int t = 0; t < 5; ++t) { Z[t] = wredsum(Z[t]); S1[t] = wredsum(S1[t]); }
  Z1 = wredsum(Z1);
  Z20 = wredsum(Z20);

  // cross-wave combine via LDS: 22 partials per wave
  __shared__ float sred[4][22];
  if (lane == 0) {
#pragma unroll
    for (int t = 0; t < 5; ++t) {
      sred[wv][t] = t1[t];
      sred[wv][5 + t] = t2[t];
      sred[wv][10 + t] = Z[t];
      sred[wv][15 + t] = S1[t];
    }
    sred[wv][20] = Z1;
    sred[wv][21] = Z20;
  }
  __syncthreads();

  if (threadIdx.x == 0) {
    float T1[5], T2[5], ZZ[5], SS[5], z1, z20;
#pragma unroll
    for (int t = 0; t < 5; ++t) {
      T1[t] = sred[0][t]; T2[t] = sred[0][5 + t];
      ZZ[t] = sred[0][10 + t]; SS[t] = sred[0][15 + t];
    }
    z1 = sred[0][20]; z20 = sred[0][21];
#pragma unroll
    for (int w = 1; w < 4; ++w) {
#pragma unroll
      for (int t = 0; t < 5; ++t) {
        float a1 = sred[w][t], a2 = sred[w][5 + t];
        float lo = fminf(T1[t], a1);
        T1[t] = fmaxf(T1[t], a1);
        T2[t] = fmaxf(fmaxf(T2[t], a2), lo);
        ZZ[t] += sred[w][10 + t];
        SS[t] += sred[w][15 + t];
      }
      z1 += sred[w][20];
      z20 += sred[w][21];
    }

    const float gm = ((g1 + g2) + g3 + g4) * 0.25f;  // same op order as wm
    float gg[5] = {g1, g2, g3, g4, gm};

    const float lse_s = flog2(z20) * LN2;      // logsumexp(out_s/20), unshifted
    const float CE = flog2(z1) * LN2 - gs;     // -log_softmax(out_s)[target]

#pragma unroll
    for (int t = 0; t < 5; ++t) {
      float lse_t = flog2(ZZ[t]) * LN2;
      float KD = 400.0f * (SS[t] / (20.0f * ZZ[t]) - lse_t + lse_s);
      float margin = (T1[t] == gg[t]) ? (T1[t] - T2[t]) : 0.0f;
      ws[(size_t)t * NB + row] = margin;
      ws[(size_t)(5 + t) * NB + row] = gg[t];
      ws[(size_t)(10 + t) * NB + row] = KD;
    }
    ws[(size_t)15 * NB + row] = CE;
    ws[(size_t)16 * NB + row] = fminf(fminf(g1, g2), fminf(g3, g4));
    ws[(size_t)17 * NB + row] = fmaxf(fmaxf(T1[0], T1[1]), fmaxf(T1[2], T1[3]));
  }
}

// Single block: global min/max over the two 8192-row arrays (64 KB) ->
// shift & maxp; also zeroes out[0] for k_loss's atomics.
__global__ __launch_bounds__(1024) void k_minmax(float* __restrict__ ws,
                                                 float* __restrict__ out) {
  const int tid = threadIdx.x;
  const int lane = tid & 63, wv = tid >> 6;
  __shared__ float sA[16], sB[16];

  float mn = INFINITY, mx = -INFINITY;
  for (int r = tid; r < NB; r += 1024) {
    mn = fminf(mn, ws[(size_t)16 * NB + r]);
    mx = fmaxf(mx, ws[(size_t)17 * NB + r]);
  }
  mn = wredmin(mn);
  mx = wredmax(mx);
  if (lane == 0) { sA[wv] = mn; sB[wv] = mx; }
  __syncthreads();
  if (tid == 0) {
    float a = sA[0], b = sB[0];
    for (int i = 1; i < 16; ++i) { a = fminf(a, sA[i]); b = fmaxf(b, sB[i]); }
    float shift = (a < 0.0f) ? (-a + 1e-5f) : 0.0f;
    ws[(size_t)18 * NB] = shift;
    ws[(size_t)18 * NB + 1] = b + shift;
    out[0] = 0.0f;
  }
}

// Multi-block weighted-loss reduction; one atomicAdd per block.
__global__ __launch_bounds__(256) void k_loss(const float* __restrict__ ws,
                                              float* __restrict__ out) {
  const int tid = threadIdx.x;
  const int lane = tid & 63, wv = tid >> 6;
  const int r = blockIdx.x * 256 + tid;   // 32 blocks x 256 = 8192 rows
  __shared__ float sA[4];

  const float shift = ws[(size_t)18 * NB];
  const float maxp = ws[(size_t)18 * NB + 1];
  const float K6 = LOG2E / 6.0f;

  float m[5], e[5];
#pragma unroll
  for (int t = 0; t < 5; ++t) m[t] = ws[(size_t)t * NB + r];
  float pm = fmaxf(fmaxf(fmaxf(m[0], m[1]), fmaxf(m[2], m[3])), m[4]);
  float Zl = 0.0f;
#pragma unroll
  for (int t = 0; t < 5; ++t) { e[t] = fexp2((m[t] - pm) * K6); Zl += e[t]; }
  float ce = ws[(size_t)15 * NB + r];
  float rl = 0.0f;
#pragma unroll
  for (int t = 0; t < 5; ++t) {
    float g = ws[(size_t)(5 + t) * NB + r];
    float kd = ws[(size_t)(10 + t) * NB + r];
    float w2 = (g + shift) / maxp;
    float loss = (1.0f - w2) * ce + w2 * kd;
    rl += e[t] * loss;
  }
  float acc = rl / Zl;

  acc = wredsum(acc);
  if (lane == 0) sA[wv] = acc;
  __syncthreads();
  if (tid == 0) {
    float tot = (sA[0] + sA[1]) + (sA[2] + sA[3]);
    atomicAdd(out, tot * (1.0f / 8192.0f));
  }
}

extern "C" void kernel_launch(void* const* d_in, const int* in_sizes, int n_in,
                              void* d_out, int out_size, void* d_ws, size_t ws_size,
                              hipStream_t stream) {
  const float* o1 = (const float*)d_in[0];
  const float* o2 = (const float*)d_in[1];
  const float* o3 = (const float*)d_in[2];
  const float* o4 = (const float*)d_in[3];
  const float* os = (const float*)d_in[4];
  const int* tg = (const int*)d_in[5];
  float* ws = (float*)d_ws;
  float* out = (float*)d_out;

  k_rowstats<<<NB, 256, 0, stream>>>(o1, o2, o3, o4, os, tg, ws);
  k_minmax<<<1, 1024, 0, stream>>>(ws, out);
  k_loss<<<NB / 256, 256, 0, stream>>>(ws, out);
}

// Round 6
// 188.227 us; speedup vs baseline: 1.7736x; 1.0317x over previous
//
#include <hip/hip_runtime.h>
#include <math.h>

#define NB 8192      // batch rows
#define NC 1000      // classes
#define NF4 250      // NC / 4 float4s per row

// ws layout (floats, stride NB):
//  [0..4]   margin per branch
//  [5..9]   gathered (raw) per branch
//  [10..14] KD per branch
//  [15]     CE
//  [16]     row min of gathered over 4 real teachers
//  [17]     row max of row-maxes over 4 real teachers
//  [18*NB + 0] shift  (written by k_minmax)
//  [18*NB + 1] maxp   (written by k_minmax)

#define LOG2E 1.4426950408889634f
#define LN2   0.6931471805599453f

__device__ __forceinline__ float fexp2(float x) { return __builtin_amdgcn_exp2f(x); }
__device__ __forceinline__ float flog2(float x) { return __builtin_amdgcn_logf(x); }

// ---------------- DPP wave reductions (VALU pipe, not DS) ----------------
// Directional reduce: row_shr 1/2/4/8 within 16-lane rows, then row_bcast:15
// (lane15->16..31, lane47->48..63) and row_bcast:31 (lane31->32..63).
// Full-wave result lands in lane 63. Invalid source lanes take `ident`
// (bound_ctrl=false, old=ident).
template <int CTRL>
__device__ __forceinline__ float dpp_mov(float v, float ident) {
  return __uint_as_float((unsigned)__builtin_amdgcn_update_dpp(
      (int)__float_as_uint(ident), (int)__float_as_uint(v), CTRL, 0xF, 0xF,
      false));
}

__device__ __forceinline__ float dppredsum(float v) {
  v += dpp_mov<0x111>(v, 0.f);
  v += dpp_mov<0x112>(v, 0.f);
  v += dpp_mov<0x114>(v, 0.f);
  v += dpp_mov<0x118>(v, 0.f);
  v += dpp_mov<0x142>(v, 0.f);
  v += dpp_mov<0x143>(v, 0.f);
  return v;  // lane 63 = full sum
}

__device__ __forceinline__ void dppredtop2(float& t1, float& t2) {
  const float NI = -INFINITY;
#define T2STEP(C)                                   \
  {                                                 \
    float i1 = dpp_mov<C>(t1, NI);                  \
    float i2 = dpp_mov<C>(t2, NI);                  \
    t2 = fmaxf(fmaxf(t2, i2), fminf(t1, i1));       \
    t1 = fmaxf(t1, i1);                             \
  }
  T2STEP(0x111) T2STEP(0x112) T2STEP(0x114) T2STEP(0x118)
  T2STEP(0x142) T2STEP(0x143)
#undef T2STEP
  // lane 63 = (max, runner-up)
}

// shfl-based helpers (only used in the tiny finalize kernels)
__device__ __forceinline__ float wredsum(float v) {
#pragma unroll
  for (int m = 32; m >= 1; m >>= 1) v += __shfl_xor(v, m, 64);
  return v;
}
__device__ __forceinline__ float wredmax(float v) {
#pragma unroll
  for (int m = 32; m >= 1; m >>= 1) v = fmaxf(v, __shfl_xor(v, m, 64));
  return v;
}
__device__ __forceinline__ float wredmin(float v) {
#pragma unroll
  for (int m = 32; m >= 1; m >>= 1) v = fminf(v, __shfl_xor(v, m, 64));
  return v;
}
__device__ __forceinline__ float f4get(const float4& v, int e) {
  return e == 0 ? v.x : e == 1 ? v.y : e == 2 ? v.z : v.w;
}

// One BLOCK (4 waves) per row; DPP reductions (DS pipe was ~60% busy with
// shfl butterflies — R5 post-mortem). No global atomics (R3/R4 lesson).
__global__ __launch_bounds__(256) void k_rowstats(
    const float* __restrict__ o1, const float* __restrict__ o2,
    const float* __restrict__ o3, const float* __restrict__ o4,
    const float* __restrict__ os, const int* __restrict__ tg,
    float* __restrict__ ws) {
  const int lane = threadIdx.x & 63;
  const int wv = threadIdx.x >> 6;         // 0..3
  const int row = blockIdx.x;
  const size_t base = (size_t)row * NC;
  const int f = (threadIdx.x < NF4) ? (int)threadIdx.x : 0;  // float4 idx
  const bool act = threadIdx.x < NF4;

  // target gathers: only wave 0 needs them — issue first, overlap bulk loads
  float g1 = 0.f, g2 = 0.f, g3 = 0.f, g4 = 0.f, gs = 0.f;
  if (wv == 0) {
    const int target = tg[row];
    g1 = o1[base + target];
    g2 = o2[base + target];
    g3 = o3[base + target];
    g4 = o4[base + target];
    gs = os[base + target];
  }

  // bulk loads: 5 float4s per lane, all in flight at once
  const float4 c1 = ((const float4*)(o1 + base))[f];
  const float4 c2 = ((const float4*)(o2 + base))[f];
  const float4 c3 = ((const float4*)(o3 + base))[f];
  const float4 c4 = ((const float4*)(o4 + base))[f];
  const float4 cs = ((const float4*)(os + base))[f];

  float t1[5], t2[5], Z[5], S1[5];
#pragma unroll
  for (int t = 0; t < 5; ++t) {
    t1[t] = -INFINITY; t2[t] = -INFINITY; Z[t] = 0.f; S1[t] = 0.f;
  }
  float Z1 = 0.f, Z20 = 0.f;
  const float K20 = LOG2E / 20.0f;

  if (act) {
#pragma unroll
    for (int e = 0; e < 4; ++e) {
      float w0 = f4get(c1, e);
      float w1 = f4get(c2, e);
      float w2 = f4get(c3, e);
      float w3 = f4get(c4, e);
      float wsv = f4get(cs, e);
      float wm = ((w0 + w1) + w2 + w3) * 0.25f;  // mimic — keep this op order
      float w[5] = {w0, w1, w2, w3, wm};
#pragma unroll
      for (int t = 0; t < 5; ++t) {
        t2[t] = fmaxf(t2[t], fminf(t1[t], w[t]));
        t1[t] = fmaxf(t1[t], w[t]);
        float et = fexp2(w[t] * K20);
        Z[t] += et;
        S1[t] = fmaf(et, w[t] - wsv, S1[t]);
      }
      Z1 += fexp2(wsv * LOG2E);
      Z20 += fexp2(wsv * K20);
    }
  }

  // wave-level reductions on the VALU pipe (result in lane 63)
#pragma unroll
  for (int t = 0; t < 5; ++t) dppredtop2(t1[t], t2[t]);
#pragma unroll
  for (int t = 0; t < 5; ++t) { Z[t] = dppredsum(Z[t]); S1[t] = dppredsum(S1[t]); }
  Z1 = dppredsum(Z1);
  Z20 = dppredsum(Z20);

  // cross-wave combine via LDS: 22 partials per wave (lane 63 holds them)
  __shared__ float sred[4][22];
  if (lane == 63) {
#pragma unroll
    for (int t = 0; t < 5; ++t) {
      sred[wv][t] = t1[t];
      sred[wv][5 + t] = t2[t];
      sred[wv][10 + t] = Z[t];
      sred[wv][15 + t] = S1[t];
    }
    sred[wv][20] = Z1;
    sred[wv][21] = Z20;
  }
  __syncthreads();

  if (threadIdx.x == 0) {
    float T1[5], T2[5], ZZ[5], SS[5], z1, z20;
#pragma unroll
    for (int t = 0; t < 5; ++t) {
      T1[t] = sred[0][t]; T2[t] = sred[0][5 + t];
      ZZ[t] = sred[0][10 + t]; SS[t] = sred[0][15 + t];
    }
    z1 = sred[0][20]; z20 = sred[0][21];
#pragma unroll
    for (int w = 1; w < 4; ++w) {
#pragma unroll
      for (int t = 0; t < 5; ++t) {
        float a1 = sred[w][t], a2 = sred[w][5 + t];
        float lo = fminf(T1[t], a1);
        T1[t] = fmaxf(T1[t], a1);
        T2[t] = fmaxf(fmaxf(T2[t], a2), lo);
        ZZ[t] += sred[w][10 + t];
        SS[t] += sred[w][15 + t];
      }
      z1 += sred[w][20];
      z20 += sred[w][21];
    }

    const float gm = ((g1 + g2) + g3 + g4) * 0.25f;  // same op order as wm
    float gg[5] = {g1, g2, g3, g4, gm};

    const float lse_s = flog2(z20) * LN2;      // logsumexp(out_s/20), unshifted
    const float CE = flog2(z1) * LN2 - gs;     // -log_softmax(out_s)[target]

#pragma unroll
    for (int t = 0; t < 5; ++t) {
      float lse_t = flog2(ZZ[t]) * LN2;
      float KD = 400.0f * (SS[t] / (20.0f * ZZ[t]) - lse_t + lse_s);
      float margin = (T1[t] == gg[t]) ? (T1[t] - T2[t]) : 0.0f;
      ws[(size_t)t * NB + row] = margin;
      ws[(size_t)(5 + t) * NB + row] = gg[t];
      ws[(size_t)(10 + t) * NB + row] = KD;
    }
    ws[(size_t)15 * NB + row] = CE;
    ws[(size_t)16 * NB + row] = fminf(fminf(g1, g2), fminf(g3, g4));
    ws[(size_t)17 * NB + row] = fmaxf(fmaxf(T1[0], T1[1]), fmaxf(T1[2], T1[3]));
  }
}

// Single block: global min/max over the two 8192-row arrays (64 KB) ->
// shift & maxp; also zeroes out[0] for k_loss's atomics.
__global__ __launch_bounds__(1024) void k_minmax(float* __restrict__ ws,
                                                 float* __restrict__ out) {
  const int tid = threadIdx.x;
  const int lane = tid & 63, wv = tid >> 6;
  __shared__ float sA[16], sB[16];

  float mn = INFINITY, mx = -INFINITY;
  for (int r = tid; r < NB; r += 1024) {
    mn = fminf(mn, ws[(size_t)16 * NB + r]);
    mx = fmaxf(mx, ws[(size_t)17 * NB + r]);
  }
  mn = wredmin(mn);
  mx = wredmax(mx);
  if (lane == 0) { sA[wv] = mn; sB[wv] = mx; }
  __syncthreads();
  if (tid == 0) {
    float a = sA[0], b = sB[0];
    for (int i = 1; i < 16; ++i) { a = fminf(a, sA[i]); b = fmaxf(b, sB[i]); }
    float shift = (a < 0.0f) ? (-a + 1e-5f) : 0.0f;
    ws[(size_t)18 * NB] = shift;
    ws[(size_t)18 * NB + 1] = b + shift;
    out[0] = 0.0f;
  }
}

// Multi-block weighted-loss reduction; one atomicAdd per block.
__global__ __launch_bounds__(256) void k_loss(const float* __restrict__ ws,
                                              float* __restrict__ out) {
  const int tid = threadIdx.x;
  const int lane = tid & 63, wv = tid >> 6;
  const int r = blockIdx.x * 256 + tid;   // 32 blocks x 256 = 8192 rows
  __shared__ float sA[4];

  const float shift = ws[(size_t)18 * NB];
  const float maxp = ws[(size_t)18 * NB + 1];
  const float K6 = LOG2E / 6.0f;

  float m[5], e[5];
#pragma unroll
  for (int t = 0; t < 5; ++t) m[t] = ws[(size_t)t * NB + r];
  float pm = fmaxf(fmaxf(fmaxf(m[0], m[1]), fmaxf(m[2], m[3])), m[4]);
  float Zl = 0.0f;
#pragma unroll
  for (int t = 0; t < 5; ++t) { e[t] = fexp2((m[t] - pm) * K6); Zl += e[t]; }
  float ce = ws[(size_t)15 * NB + r];
  float rl = 0.0f;
#pragma unroll
  for (int t = 0; t < 5; ++t) {
    float g = ws[(size_t)(5 + t) * NB + r];
    float kd = ws[(size_t)(10 + t) * NB + r];
    float w2 = (g + shift) / maxp;
    float loss = (1.0f - w2) * ce + w2 * kd;
    rl += e[t] * loss;
  }
  float acc = rl / Zl;

  acc = wredsum(acc);
  if (lane == 0) sA[wv] = acc;
  __syncthreads();
  if (tid == 0) {
    float tot = (sA[0] + sA[1]) + (sA[2] + sA[3]);
    atomicAdd(out, tot * (1.0f / 8192.0f));
  }
}

extern "C" void kernel_launch(void* const* d_in, const int* in_sizes, int n_in,
                              void* d_out, int out_size, void* d_ws, size_t ws_size,
                              hipStream_t stream) {
  const float* o1 = (const float*)d_in[0];
  const float* o2 = (const float*)d_in[1];
  const float* o3 = (const float*)d_in[2];
  const float* o4 = (const float*)d_in[3];
  const float* os = (const float*)d_in[4];
  const int* tg = (const int*)d_in[5];
  float* ws = (float*)d_ws;
  float* out = (float*)d_out;

  k_rowstats<<<NB, 256, 0, stream>>>(o1, o2, o3, o4, os, tg, ws);
  k_minmax<<<1, 1024, 0, stream>>>(ws, out);
  k_loss<<<NB / 256, 256, 0, stream>>>(ws, out);
}